// Round 2
// baseline (1860.285 us; speedup 1.0000x reference)
//
#include <hip/hip_runtime.h>
#include <hip/hip_bf16.h>
#include <math.h>

typedef __bf16 bf16_t;
typedef __bf16 bf16x4 __attribute__((ext_vector_type(4)));
typedef __bf16 bf16x8 __attribute__((ext_vector_type(8)));
typedef float  f32x4  __attribute__((ext_vector_type(4)));

#define DIN   3072
#define NOUT  24576
#define HALF  12288
#define MTOK  4096
#define BM    128
#define BN    128
#define BK    64

#define GLD16(gp, lp) \
    __builtin_amdgcn_global_load_lds((const __attribute__((address_space(1))) void*)(gp), \
                                     (__attribute__((address_space(3))) void*)(lp), 16, 0, 0)

// ---------------- K1: per-token activation int4 fake-quant -> bf16 ----------------
__global__ __launch_bounds__(256) void k_quant_x(const float* __restrict__ x,
                                                 bf16_t* __restrict__ xq) {
    int m = blockIdx.x;
    int t = threadIdx.x;
    const float4* row = reinterpret_cast<const float4*>(x + (size_t)m * DIN);
    float4 v[3];
    float vm = 0.f;
#pragma unroll
    for (int i = 0; i < 3; ++i) {
        v[i] = row[t + i * 256];
        vm = fmaxf(vm, fmaxf(fmaxf(fabsf(v[i].x), fabsf(v[i].y)),
                             fmaxf(fabsf(v[i].z), fabsf(v[i].w))));
    }
#pragma unroll
    for (int d = 1; d < 64; d <<= 1) vm = fmaxf(vm, __shfl_xor(vm, d));
    __shared__ float sm[4];
    if ((t & 63) == 0) sm[t >> 6] = vm;
    __syncthreads();
    vm = fmaxf(fmaxf(sm[0], sm[1]), fmaxf(sm[2], sm[3]));
    float s = fmaxf(vm * (1.f / 7.f), 1e-8f);
    float inv = 1.f / s;
    bf16x4* orow = reinterpret_cast<bf16x4*>(xq + (size_t)m * DIN);
#pragma unroll
    for (int i = 0; i < 3; ++i) {
        bf16x4 o;
        o[0] = (bf16_t)(fminf(fmaxf(rintf(v[i].x * inv), -8.f), 7.f) * s);
        o[1] = (bf16_t)(fminf(fmaxf(rintf(v[i].y * inv), -8.f), 7.f) * s);
        o[2] = (bf16_t)(fminf(fmaxf(rintf(v[i].z * inv), -8.f), 7.f) * s);
        o[3] = (bf16_t)(fminf(fmaxf(rintf(v[i].w * inv), -8.f), 7.f) * s);
        orow[t + i * 256] = o;
    }
}

// ---------------- K2: per-(row, group-of-64) weight int4 fake-quant -> bf16 -------
// One thread = one float4 (4 elems); 16 consecutive lanes = one group of 64.
__global__ __launch_bounds__(256) void k_quant_w(const float* __restrict__ w,
                                                 bf16_t* __restrict__ wq) {
    size_t idx = (size_t)blockIdx.x * 256 + threadIdx.x;  // float4 index
    float4 v = reinterpret_cast<const float4*>(w)[idx];
    float vm = fmaxf(fmaxf(fabsf(v.x), fabsf(v.y)), fmaxf(fabsf(v.z), fabsf(v.w)));
    vm = fmaxf(vm, __shfl_xor(vm, 1));
    vm = fmaxf(vm, __shfl_xor(vm, 2));
    vm = fmaxf(vm, __shfl_xor(vm, 4));
    vm = fmaxf(vm, __shfl_xor(vm, 8));
    float s = fmaxf(vm * (1.f / 7.f), 1e-8f);
    float inv = 1.f / s;
    bf16x4 o;
    o[0] = (bf16_t)(fminf(fmaxf(rintf(v.x * inv), -8.f), 7.f) * s);
    o[1] = (bf16_t)(fminf(fmaxf(rintf(v.y * inv), -8.f), 7.f) * s);
    o[2] = (bf16_t)(fminf(fmaxf(rintf(v.z * inv), -8.f), 7.f) * s);
    o[3] = (bf16_t)(fminf(fmaxf(rintf(v.w * inv), -8.f), 7.f) * s);
    reinterpret_cast<bf16x4*>(wq)[idx] = o;
}

// ---------------- K3: T = x @ lora_down^T  (full-precision x), bf16 out -----------
__global__ __launch_bounds__(256) void k_lora_t(const float* __restrict__ x,
                                                const float* __restrict__ ld,
                                                bf16_t* __restrict__ T) {
    int r = threadIdx.x & 31;
    int m = blockIdx.x * 8 + (threadIdx.x >> 5);
    const float4* xr = reinterpret_cast<const float4*>(x + (size_t)m * DIN);
    const float4* lr = reinterpret_cast<const float4*>(ld + (size_t)r * DIN);
    float acc = 0.f;
#pragma unroll 4
    for (int i = 0; i < DIN / 4; ++i) {
        float4 a = xr[i], b = lr[i];
        acc += a.x * b.x + a.y * b.y + a.z * b.z + a.w * b.w;
    }
    T[(size_t)m * 32 + r] = (bf16_t)acc;
}

// ---------------- K3b: cast lora_up f32 -> bf16 -----------------------------------
__global__ __launch_bounds__(256) void k_cvt_lu(const float* __restrict__ lu,
                                                bf16_t* __restrict__ lub) {
    size_t idx = (size_t)blockIdx.x * 256 + threadIdx.x;  // float4 index
    float4 v = reinterpret_cast<const float4*>(lu)[idx];
    bf16x4 o;
    o[0] = (bf16_t)v.x; o[1] = (bf16_t)v.y; o[2] = (bf16_t)v.z; o[3] = (bf16_t)v.w;
    reinterpret_cast<bf16x4*>(lub)[idx] = o;
}

// ---------------- K4: fused GEMM (h + gate tiles) + LoRA + GEGLU ------------------
// grid = 32 mtiles * 96 ntiles; block = 256 thr = 4 waves (2x2); per wave 64x64 per tile-half.
__global__ __launch_bounds__(256) void k_gemm(const bf16_t* __restrict__ xq,
                                              const bf16_t* __restrict__ wq,
                                              const bf16_t* __restrict__ T,
                                              const bf16_t* __restrict__ lub,
                                              float* __restrict__ out) {
    __shared__ bf16_t sA[BM * BK];
    __shared__ bf16_t sH[BN * BK];
    __shared__ bf16_t sG[BN * BK];

    int tid = threadIdx.x, lane = tid & 63, w = tid >> 6;
    // XCD-bijective swizzle (3072 % 8 == 0)
    int nwg = gridDim.x;
    int cpx = nwg >> 3;
    int swz = (blockIdx.x & 7) * cpx + (blockIdx.x >> 3);
    int mt = swz & 31, nt = swz >> 5;          // mt fast: neighbors share B tiles
    int m0 = mt * BM, c0 = nt * BN;
    int wr = w >> 1, wc = w & 1;

    f32x4 accH[4][4], accG[4][4];
#pragma unroll
    for (int i = 0; i < 4; ++i)
#pragma unroll
        for (int j = 0; j < 4; ++j) {
            accH[i][j] = (f32x4){0.f, 0.f, 0.f, 0.f};
            accG[i][j] = (f32x4){0.f, 0.f, 0.f, 0.f};
        }

    int lrow = lane >> 3;                // 0..7
    int lcol = (lane & 7) * 8;           // 0..56, 8 bf16 = 16B per lane

    for (int k0 = 0; k0 < DIN; k0 += BK) {
        __syncthreads();
#pragma unroll
        for (int i = 0; i < 4; ++i) {
            int rbase = i * 32 + w * 8;
            GLD16(xq + (size_t)(m0 + rbase + lrow) * DIN + k0 + lcol, sA + rbase * BK);
        }
#pragma unroll
        for (int i = 0; i < 4; ++i) {
            int rbase = i * 32 + w * 8;
            GLD16(wq + (size_t)(c0 + rbase + lrow) * DIN + k0 + lcol, sH + rbase * BK);
        }
#pragma unroll
        for (int i = 0; i < 4; ++i) {
            int rbase = i * 32 + w * 8;
            GLD16(wq + (size_t)(c0 + HALF + rbase + lrow) * DIN + k0 + lcol, sG + rbase * BK);
        }
        __syncthreads();   // vmcnt(0) drain before barrier

#pragma unroll
        for (int ks = 0; ks < 2; ++ks) {
            int kb = ks * 32 + (lane >> 4) * 8;
            bf16x8 a[4], bh[4], bg[4];
#pragma unroll
            for (int i = 0; i < 4; ++i) {
                a[i]  = *reinterpret_cast<const bf16x8*>(sA + (wr * 64 + i * 16 + (lane & 15)) * BK + kb);
                bh[i] = *reinterpret_cast<const bf16x8*>(sH + (wc * 64 + i * 16 + (lane & 15)) * BK + kb);
                bg[i] = *reinterpret_cast<const bf16x8*>(sG + (wc * 64 + i * 16 + (lane & 15)) * BK + kb);
            }
#pragma unroll
            for (int m = 0; m < 4; ++m)
#pragma unroll
                for (int n = 0; n < 4; ++n) {
                    accH[m][n] = __builtin_amdgcn_mfma_f32_16x16x32_bf16(a[m], bh[n], accH[m][n], 0, 0, 0);
                    accG[m][n] = __builtin_amdgcn_mfma_f32_16x16x32_bf16(a[m], bg[n], accG[m][n], 0, 0, 0);
                }
        }
    }

    // ---- LoRA correction: one K=32 MFMA per fragment (RANK == 32) ----
    bf16x8 tf[4];
#pragma unroll
    for (int m = 0; m < 4; ++m)
        tf[m] = *reinterpret_cast<const bf16x8*>(T + (size_t)(m0 + wr * 64 + m * 16 + (lane & 15)) * 32 + (lane >> 4) * 8);
#pragma unroll
    for (int n = 0; n < 4; ++n) {
        bf16x8 luh = *reinterpret_cast<const bf16x8*>(lub + (size_t)(c0 + wc * 64 + n * 16 + (lane & 15)) * 32 + (lane >> 4) * 8);
        bf16x8 lug = *reinterpret_cast<const bf16x8*>(lub + (size_t)(c0 + HALF + wc * 64 + n * 16 + (lane & 15)) * 32 + (lane >> 4) * 8);
#pragma unroll
        for (int m = 0; m < 4; ++m) {
            accH[m][n] = __builtin_amdgcn_mfma_f32_16x16x32_bf16(tf[m], luh, accH[m][n], 0, 0, 0);
            accG[m][n] = __builtin_amdgcn_mfma_f32_16x16x32_bf16(tf[m], lug, accG[m][n], 0, 0, 0);
        }
    }

    // ---- GEGLU epilogue: out = h * 0.5*g*(1+erf(g/sqrt(2))), f32 store ----
#pragma unroll
    for (int m = 0; m < 4; ++m)
#pragma unroll
        for (int n = 0; n < 4; ++n) {
            int row = m0 + wr * 64 + m * 16 + (lane >> 4) * 4;
            int col = c0 + wc * 64 + n * 16 + (lane & 15);
#pragma unroll
            for (int r = 0; r < 4; ++r) {
                float h = accH[m][n][r];
                float g = accG[m][n][r];
                float gl = 0.5f * g * (1.0f + erff(g * 0.70710678118654752f));
                out[(size_t)(row + r) * HALF + col] = h * gl;
            }
        }
}

extern "C" void kernel_launch(void* const* d_in, const int* in_sizes, int n_in,
                              void* d_out, int out_size, void* d_ws, size_t ws_size,
                              hipStream_t stream) {
    const float* x  = (const float*)d_in[0];   // [1,4096,3072]
    const float* wr = (const float*)d_in[1];   // [24576,3072]
    const float* ld = (const float*)d_in[2];   // [32,3072]
    const float* lu = (const float*)d_in[3];   // [24576,32]
    float* out = (float*)d_out;                // [4096,12288] f32  (reference is f32!)

    // workspace layout (all bf16): xq | wq | T | lub  = ~178 MiB
    bf16_t* xq  = (bf16_t*)d_ws;
    bf16_t* wq  = xq + (size_t)MTOK * DIN;
    bf16_t* T   = wq + (size_t)NOUT * DIN;
    bf16_t* lub = T  + (size_t)MTOK * 32;

    k_quant_x<<<MTOK, 256, 0, stream>>>(x, xq);
    k_quant_w<<<(NOUT * (DIN / 4)) / 256, 256, 0, stream>>>(wr, wq);
    k_lora_t<<<MTOK / 8, 256, 0, stream>>>(x, ld, T);
    k_cvt_lu<<<(NOUT * 32 / 4) / 256, 256, 0, stream>>>(lu, lub);
    k_gemm<<<(MTOK / BM) * (HALF / BN), 256, 0, stream>>>(xq, wq, T, lub, out);
}

// Round 3
// 922.720 us; speedup vs baseline: 2.0161x; 2.0161x over previous
//
#include <hip/hip_runtime.h>
#include <hip/hip_bf16.h>
#include <math.h>

typedef __bf16 bf16_t;
typedef __bf16 bf16x4 __attribute__((ext_vector_type(4)));
typedef __bf16 bf16x8 __attribute__((ext_vector_type(8)));
typedef float  f32x4  __attribute__((ext_vector_type(4)));

#define DIN   3072
#define NOUT  24576
#define HALF  12288
#define MTOK  4096
#define BM    128
#define BN    128
#define BK    64

#define GLD16(gp, lp) \
    __builtin_amdgcn_global_load_lds((const __attribute__((address_space(1))) void*)(gp), \
                                     (__attribute__((address_space(3))) void*)(lp), 16, 0, 0)

// ---------------- K1: per-token activation int4 fake-quant -> bf16 ----------------
__global__ __launch_bounds__(256) void k_quant_x(const float* __restrict__ x,
                                                 bf16_t* __restrict__ xq) {
    int m = blockIdx.x;
    int t = threadIdx.x;
    const float4* row = reinterpret_cast<const float4*>(x + (size_t)m * DIN);
    float4 v[3];
    float vm = 0.f;
#pragma unroll
    for (int i = 0; i < 3; ++i) {
        v[i] = row[t + i * 256];
        vm = fmaxf(vm, fmaxf(fmaxf(fabsf(v[i].x), fabsf(v[i].y)),
                             fmaxf(fabsf(v[i].z), fabsf(v[i].w))));
    }
#pragma unroll
    for (int d = 1; d < 64; d <<= 1) vm = fmaxf(vm, __shfl_xor(vm, d));
    __shared__ float sm[4];
    if ((t & 63) == 0) sm[t >> 6] = vm;
    __syncthreads();
    vm = fmaxf(fmaxf(sm[0], sm[1]), fmaxf(sm[2], sm[3]));
    float s = fmaxf(vm * (1.f / 7.f), 1e-8f);
    float inv = 1.f / s;
    bf16x4* orow = reinterpret_cast<bf16x4*>(xq + (size_t)m * DIN);
#pragma unroll
    for (int i = 0; i < 3; ++i) {
        bf16x4 o;
        o[0] = (bf16_t)(fminf(fmaxf(rintf(v[i].x * inv), -8.f), 7.f) * s);
        o[1] = (bf16_t)(fminf(fmaxf(rintf(v[i].y * inv), -8.f), 7.f) * s);
        o[2] = (bf16_t)(fminf(fmaxf(rintf(v[i].z * inv), -8.f), 7.f) * s);
        o[3] = (bf16_t)(fminf(fmaxf(rintf(v[i].w * inv), -8.f), 7.f) * s);
        orow[t + i * 256] = o;
    }
}

// ---------------- K2: per-(row, group-of-64) weight int4 fake-quant -> bf16 -------
__global__ __launch_bounds__(256) void k_quant_w(const float* __restrict__ w,
                                                 bf16_t* __restrict__ wq) {
    size_t idx = (size_t)blockIdx.x * 256 + threadIdx.x;  // float4 index
    float4 v = reinterpret_cast<const float4*>(w)[idx];
    float vm = fmaxf(fmaxf(fabsf(v.x), fabsf(v.y)), fmaxf(fabsf(v.z), fabsf(v.w)));
    vm = fmaxf(vm, __shfl_xor(vm, 1));
    vm = fmaxf(vm, __shfl_xor(vm, 2));
    vm = fmaxf(vm, __shfl_xor(vm, 4));
    vm = fmaxf(vm, __shfl_xor(vm, 8));
    float s = fmaxf(vm * (1.f / 7.f), 1e-8f);
    float inv = 1.f / s;
    bf16x4 o;
    o[0] = (bf16_t)(fminf(fmaxf(rintf(v.x * inv), -8.f), 7.f) * s);
    o[1] = (bf16_t)(fminf(fmaxf(rintf(v.y * inv), -8.f), 7.f) * s);
    o[2] = (bf16_t)(fminf(fmaxf(rintf(v.z * inv), -8.f), 7.f) * s);
    o[3] = (bf16_t)(fminf(fmaxf(rintf(v.w * inv), -8.f), 7.f) * s);
    reinterpret_cast<bf16x4*>(wq)[idx] = o;
}

// ---------------- K3: T = x @ lora_down^T  (full-precision x), bf16 out -----------
__global__ __launch_bounds__(256) void k_lora_t(const float* __restrict__ x,
                                                const float* __restrict__ ld,
                                                bf16_t* __restrict__ T) {
    int r = threadIdx.x & 31;
    int m = blockIdx.x * 8 + (threadIdx.x >> 5);
    const float4* xr = reinterpret_cast<const float4*>(x + (size_t)m * DIN);
    const float4* lr = reinterpret_cast<const float4*>(ld + (size_t)r * DIN);
    float acc = 0.f;
#pragma unroll 4
    for (int i = 0; i < DIN / 4; ++i) {
        float4 a = xr[i], b = lr[i];
        acc += a.x * b.x + a.y * b.y + a.z * b.z + a.w * b.w;
    }
    T[(size_t)m * 32 + r] = (bf16_t)acc;
}

// ---------------- K3b: cast lora_up f32 -> bf16 -----------------------------------
__global__ __launch_bounds__(256) void k_cvt_lu(const float* __restrict__ lu,
                                                bf16_t* __restrict__ lub) {
    size_t idx = (size_t)blockIdx.x * 256 + threadIdx.x;  // float4 index
    float4 v = reinterpret_cast<const float4*>(lu)[idx];
    bf16x4 o;
    o[0] = (bf16_t)v.x; o[1] = (bf16_t)v.y; o[2] = (bf16_t)v.z; o[3] = (bf16_t)v.w;
    reinterpret_cast<bf16x4*>(lub)[idx] = o;
}

// ---------------- K4: fused GEMM (h + gate tiles) + LoRA + GEGLU ------------------
// 512 thr = 8 waves. Waves 0-3: H tile (2x2 of 64x64); waves 4-7: G tile.
// Both-sides XOR swizzle: global source chunk col ^= row&7; ds_read col16 ^= row&7.
__global__ __launch_bounds__(512, 2) void k_gemm(const bf16_t* __restrict__ xq,
                                                 const bf16_t* __restrict__ wq,
                                                 const bf16_t* __restrict__ T,
                                                 const bf16_t* __restrict__ lub,
                                                 float* __restrict__ out) {
    __shared__ __align__(16) char smem[65536];       // staging 48KB; epilogue exch 64KB
    bf16_t* sA = (bf16_t*)smem;                      // [128][64]
    bf16_t* sH = sA + BM * BK;
    bf16_t* sG = sH + BN * BK;

    int tid = threadIdx.x, lane = tid & 63, w = tid >> 6;
    int half = w >> 2;                 // 0 = H, 1 = G
    int wr = (w & 3) >> 1, wc = w & 1;

    // XCD-bijective swizzle (3072 % 8 == 0)
    int nwg = gridDim.x;
    int cpx = nwg >> 3;
    int swz = (blockIdx.x & 7) * cpx + (blockIdx.x >> 3);
    int mt = swz & 31, nt = swz >> 5;  // mt fast: neighbors share B tiles
    int m0 = mt * BM, c0 = nt * BN;

    f32x4 acc[4][4];
#pragma unroll
    for (int i = 0; i < 4; ++i)
#pragma unroll
        for (int j = 0; j < 4; ++j) acc[i][j] = (f32x4){0.f, 0.f, 0.f, 0.f};

    const bf16_t* bsrc = wq + (size_t)(c0 + half * HALF) * DIN;  // this wave-group's B panel
    const char* sBb = (const char*)(half ? sG : sH);
    const char* sAb = (const char*)sA;

    for (int k0 = 0; k0 < DIN; k0 += BK) {
        __syncthreads();
        // stage 3 tiles of 128x64 bf16; 1024 16B-chunks each; 512 lanes -> 2 rounds.
        // source col pre-swizzled: gc16 = (chunk&7) ^ (row&7)  (rule #21: swizzle
        // BOTH the global source and the ds_read, LDS dest stays linear)
#pragma unroll
        for (int r = 0; r < 2; ++r) {
            int chunk = r * 512 + tid;
            int row = chunk >> 3;
            int gc = ((chunk & 7) ^ (row & 7)) * 8;
            int ldsoff = r * 4096 + w * 512;
            GLD16(xq + (size_t)(m0 + row) * DIN + k0 + gc, sA + ldsoff);
            GLD16(wq + (size_t)(c0 + row) * DIN + k0 + gc, sH + ldsoff);
            GLD16(wq + (size_t)(c0 + HALF + row) * DIN + k0 + gc, sG + ldsoff);
        }
        __syncthreads();   // vmcnt(0) drain before barrier

#pragma unroll
        for (int ks = 0; ks < 2; ++ks) {
            int c16 = ks * 4 + (lane >> 4);
            bf16x8 a[4], b[4];
#pragma unroll
            for (int i = 0; i < 4; ++i) {
                int ra = wr * 64 + i * 16 + (lane & 15);
                int rb = wc * 64 + i * 16 + (lane & 15);
                a[i] = *reinterpret_cast<const bf16x8*>(sAb + ra * 128 + ((c16 ^ (ra & 7)) << 4));
                b[i] = *reinterpret_cast<const bf16x8*>(sBb + rb * 128 + ((c16 ^ (rb & 7)) << 4));
            }
#pragma unroll
            for (int m = 0; m < 4; ++m)
#pragma unroll
                for (int n = 0; n < 4; ++n)
                    acc[m][n] = __builtin_amdgcn_mfma_f32_16x16x32_bf16(a[m], b[n], acc[m][n], 0, 0, 0);
        }
    }

    // ---- LoRA correction: one K=32 MFMA per fragment (RANK == 32) ----
    {
        bf16x8 tf[4];
#pragma unroll
        for (int m = 0; m < 4; ++m)
            tf[m] = *reinterpret_cast<const bf16x8*>(
                T + (size_t)(m0 + wr * 64 + m * 16 + (lane & 15)) * 32 + (lane >> 4) * 8);
#pragma unroll
        for (int n = 0; n < 4; ++n) {
            bf16x8 lu = *reinterpret_cast<const bf16x8*>(
                lub + (size_t)(c0 + half * HALF + wc * 64 + n * 16 + (lane & 15)) * 32 + (lane >> 4) * 8);
#pragma unroll
            for (int m = 0; m < 4; ++m)
                acc[m][n] = __builtin_amdgcn_mfma_f32_16x16x32_bf16(tf[m], lu, acc[m][n], 0, 0, 0);
        }
    }

    // ---- GEGLU epilogue via LDS exchange: G waves write gelu(g); H waves combine --
    __syncthreads();                    // all LDS staging reads done; reuse smem
    float* exch = (float*)smem;         // [128][128] f32, col XOR-swizzled
    if (half) {
#pragma unroll
        for (int m = 0; m < 4; ++m)
#pragma unroll
            for (int n = 0; n < 4; ++n) {
                int col = wc * 64 + n * 16 + (lane & 15);
#pragma unroll
                for (int r = 0; r < 4; ++r) {
                    int row = wr * 64 + m * 16 + (lane >> 4) * 4 + r;
                    float g = acc[m][n][r];
                    float gl = 0.5f * g * (1.0f + erff(g * 0.70710678118654752f));
                    exch[row * 128 + (col ^ (((row >> 2) & 3) << 4))] = gl;
                }
            }
    }
    __syncthreads();
    if (!half) {
#pragma unroll
        for (int m = 0; m < 4; ++m)
#pragma unroll
            for (int n = 0; n < 4; ++n) {
                int col = wc * 64 + n * 16 + (lane & 15);
#pragma unroll
                for (int r = 0; r < 4; ++r) {
                    int row = wr * 64 + m * 16 + (lane >> 4) * 4 + r;
                    float gl = exch[row * 128 + (col ^ (((row >> 2) & 3) << 4))];
                    out[(size_t)(m0 + row) * HALF + c0 + col] = acc[m][n][r] * gl;
                }
            }
    }
}

extern "C" void kernel_launch(void* const* d_in, const int* in_sizes, int n_in,
                              void* d_out, int out_size, void* d_ws, size_t ws_size,
                              hipStream_t stream) {
    const float* x  = (const float*)d_in[0];   // [1,4096,3072]
    const float* wr = (const float*)d_in[1];   // [24576,3072]
    const float* ld = (const float*)d_in[2];   // [32,3072]
    const float* lu = (const float*)d_in[3];   // [24576,32]
    float* out = (float*)d_out;                // [4096,12288] f32

    bf16_t* xq  = (bf16_t*)d_ws;
    bf16_t* wq  = xq + (size_t)MTOK * DIN;
    bf16_t* T   = wq + (size_t)NOUT * DIN;
    bf16_t* lub = T  + (size_t)MTOK * 32;

    k_quant_x<<<MTOK, 256, 0, stream>>>(x, xq);
    k_quant_w<<<(NOUT * (DIN / 4)) / 256, 256, 0, stream>>>(wr, wq);
    k_lora_t<<<MTOK / 8, 256, 0, stream>>>(x, ld, T);
    k_cvt_lu<<<(NOUT * 32 / 4) / 256, 256, 0, stream>>>(lu, lub);
    k_gemm<<<(MTOK / BM) * (HALF / BN), 512, 0, stream>>>(xq, wq, T, lub, out);
}

// Round 4
// 891.048 us; speedup vs baseline: 2.0878x; 1.0355x over previous
//
#include <hip/hip_runtime.h>
#include <hip/hip_bf16.h>
#include <math.h>

typedef __bf16 bf16_t;
typedef __bf16 bf16x4 __attribute__((ext_vector_type(4)));
typedef __bf16 bf16x8 __attribute__((ext_vector_type(8)));
typedef float  f32x4  __attribute__((ext_vector_type(4)));

#define DIN   3072
#define NOUT  24576
#define HALF  12288
#define MTOK  4096
#define BK    64
#define NT    48          // DIN / BK

#define GLD16(gp, lp) \
    __builtin_amdgcn_global_load_lds((const __attribute__((address_space(1))) void*)(gp), \
                                     (__attribute__((address_space(3))) void*)(lp), 16, 0, 0)

#define BAR()    __builtin_amdgcn_s_barrier()
#define LGKM0()  asm volatile("s_waitcnt lgkmcnt(0)" ::: "memory")
#define WAITV(N) asm volatile("s_waitcnt vmcnt(" #N ")" ::: "memory")
#define PRIO1()  __builtin_amdgcn_s_setprio(1)
#define PRIO0()  __builtin_amdgcn_s_setprio(0)

// ---------------- K1: per-token activation int4 fake-quant -> bf16 ----------------
__global__ __launch_bounds__(256) void k_quant_x(const float* __restrict__ x,
                                                 bf16_t* __restrict__ xq) {
    int m = blockIdx.x;
    int t = threadIdx.x;
    const float4* row = reinterpret_cast<const float4*>(x + (size_t)m * DIN);
    float4 v[3];
    float vm = 0.f;
#pragma unroll
    for (int i = 0; i < 3; ++i) {
        v[i] = row[t + i * 256];
        vm = fmaxf(vm, fmaxf(fmaxf(fabsf(v[i].x), fabsf(v[i].y)),
                             fmaxf(fabsf(v[i].z), fabsf(v[i].w))));
    }
#pragma unroll
    for (int d = 1; d < 64; d <<= 1) vm = fmaxf(vm, __shfl_xor(vm, d));
    __shared__ float sm[4];
    if ((t & 63) == 0) sm[t >> 6] = vm;
    __syncthreads();
    vm = fmaxf(fmaxf(sm[0], sm[1]), fmaxf(sm[2], sm[3]));
    float s = fmaxf(vm * (1.f / 7.f), 1e-8f);
    float inv = 1.f / s;
    bf16x4* orow = reinterpret_cast<bf16x4*>(xq + (size_t)m * DIN);
#pragma unroll
    for (int i = 0; i < 3; ++i) {
        bf16x4 o;
        o[0] = (bf16_t)(fminf(fmaxf(rintf(v[i].x * inv), -8.f), 7.f) * s);
        o[1] = (bf16_t)(fminf(fmaxf(rintf(v[i].y * inv), -8.f), 7.f) * s);
        o[2] = (bf16_t)(fminf(fmaxf(rintf(v[i].z * inv), -8.f), 7.f) * s);
        o[3] = (bf16_t)(fminf(fmaxf(rintf(v[i].w * inv), -8.f), 7.f) * s);
        orow[t + i * 256] = o;
    }
}

// ---------------- K2: per-(row, group-of-64) weight int4 fake-quant -> bf16 -------
__global__ __launch_bounds__(256) void k_quant_w(const float* __restrict__ w,
                                                 bf16_t* __restrict__ wq) {
    size_t idx = (size_t)blockIdx.x * 256 + threadIdx.x;  // float4 index
    float4 v = reinterpret_cast<const float4*>(w)[idx];
    float vm = fmaxf(fmaxf(fabsf(v.x), fabsf(v.y)), fmaxf(fabsf(v.z), fabsf(v.w)));
    vm = fmaxf(vm, __shfl_xor(vm, 1));
    vm = fmaxf(vm, __shfl_xor(vm, 2));
    vm = fmaxf(vm, __shfl_xor(vm, 4));
    vm = fmaxf(vm, __shfl_xor(vm, 8));
    float s = fmaxf(vm * (1.f / 7.f), 1e-8f);
    float inv = 1.f / s;
    bf16x4 o;
    o[0] = (bf16_t)(fminf(fmaxf(rintf(v.x * inv), -8.f), 7.f) * s);
    o[1] = (bf16_t)(fminf(fmaxf(rintf(v.y * inv), -8.f), 7.f) * s);
    o[2] = (bf16_t)(fminf(fmaxf(rintf(v.z * inv), -8.f), 7.f) * s);
    o[3] = (bf16_t)(fminf(fmaxf(rintf(v.w * inv), -8.f), 7.f) * s);
    reinterpret_cast<bf16x4*>(wq)[idx] = o;
}

// ---------------- K3: T = x @ lora_down^T  (full-precision x), bf16 out -----------
__global__ __launch_bounds__(256) void k_lora_t(const float* __restrict__ x,
                                                const float* __restrict__ ld,
                                                bf16_t* __restrict__ T) {
    int r = threadIdx.x & 31;
    int m = blockIdx.x * 8 + (threadIdx.x >> 5);
    const float4* xr = reinterpret_cast<const float4*>(x + (size_t)m * DIN);
    const float4* lr = reinterpret_cast<const float4*>(ld + (size_t)r * DIN);
    float acc = 0.f;
#pragma unroll 4
    for (int i = 0; i < DIN / 4; ++i) {
        float4 a = xr[i], b = lr[i];
        acc += a.x * b.x + a.y * b.y + a.z * b.z + a.w * b.w;
    }
    T[(size_t)m * 32 + r] = (bf16_t)acc;
}

// ---------------- K3b: cast lora_up f32 -> bf16 -----------------------------------
__global__ __launch_bounds__(256) void k_cvt_lu(const float* __restrict__ lu,
                                                bf16_t* __restrict__ lub) {
    size_t idx = (size_t)blockIdx.x * 256 + threadIdx.x;  // float4 index
    float4 v = reinterpret_cast<const float4*>(lu)[idx];
    bf16x4 o;
    o[0] = (bf16_t)v.x; o[1] = (bf16_t)v.y; o[2] = (bf16_t)v.z; o[3] = (bf16_t)v.w;
    reinterpret_cast<bf16x4*>(lub)[idx] = o;
}

// ---------------- K4: 8-phase-style fused GEMM (T2+T3+T4+T5) ----------------------
// Tile 256 rows x (128 H-cols + 128 G-cols). 512 thr = 8 waves: 0-3 H, 4-7 G,
// each group 2x2 over 256x128 (per-wave 128x64 = 8 Mfrag x 4 Nfrag).
// LDS dbuf 2 x {A 32K | BH 16K | BG 16K} = 128 KB. 4 phases/K-tile, counted vmcnt.
// Stage units per K-tile: P0->A-half0, P1->BH, P2->BG, P3->A-half1 (2 GLD16 each).
// Waits: end-P3 vmcnt(2) (next A0/BH/BG done), end-P1 vmcnt(4) (cur A1 done);
// each wait precedes a barrier -> cross-wave completion.

#define STAGE_UNIT(gbase, sbase)                                              \
    do {                                                                      \
        _Pragma("unroll")                                                     \
        for (int _r = 0; _r < 2; ++_r) {                                      \
            int _c = _r * 512 + tid;                                          \
            int _row = _c >> 3;                                               \
            int _gc = ((_c & 7) ^ (_row & 7)) * 8;                            \
            GLD16((gbase) + (size_t)_row * DIN + _gc, (sbase) + _c * 16);     \
        }                                                                     \
    } while (0)

#define LOAD_A(mh)                                                            \
    _Pragma("unroll")                                                         \
    for (int _i = 0; _i < 4; ++_i) {                                          \
        _Pragma("unroll")                                                     \
        for (int _ks = 0; _ks < 2; ++_ks) {                                   \
            int _ra = (mh) * 128 + wr * 64 + _i * 16 + l15;                   \
            int _c16 = _ks * 4 + lhi;                                         \
            a[_i][_ks] = *(const bf16x8*)(sAc + _ra * 128 + ((_c16 ^ lk) << 4)); \
        }                                                                     \
    }

#define LOAD_B(nh)                                                            \
    _Pragma("unroll")                                                         \
    for (int _j = 0; _j < 2; ++_j) {                                          \
        _Pragma("unroll")                                                     \
        for (int _ks = 0; _ks < 2; ++_ks) {                                   \
            int _rb = wc * 64 + ((nh) * 2 + _j) * 16 + l15;                   \
            int _c16 = _ks * 4 + lhi;                                         \
            b[(nh) * 2 + _j][_ks] = *(const bf16x8*)(sBc + _rb * 128 + ((_c16 ^ lk) << 4)); \
        }                                                                     \
    }

#define MFMA_Q(mh, nh)                                                        \
    _Pragma("unroll")                                                         \
    for (int _i = 0; _i < 4; ++_i) {                                          \
        _Pragma("unroll")                                                     \
        for (int _j = 0; _j < 2; ++_j) {                                      \
            _Pragma("unroll")                                                 \
            for (int _ks = 0; _ks < 2; ++_ks) {                               \
                acc[(mh) * 4 + _i][(nh) * 2 + _j] =                           \
                    __builtin_amdgcn_mfma_f32_16x16x32_bf16(                  \
                        a[_i][_ks], b[(nh) * 2 + _j][_ks],                    \
                        acc[(mh) * 4 + _i][(nh) * 2 + _j], 0, 0, 0);          \
            }                                                                 \
        }                                                                     \
    }

__global__ __launch_bounds__(512, 2) void k_gemm(const bf16_t* __restrict__ xq,
                                                 const bf16_t* __restrict__ wq,
                                                 const bf16_t* __restrict__ T,
                                                 const bf16_t* __restrict__ lub,
                                                 float* __restrict__ out) {
    __shared__ __align__(16) char smem[131072];

    const int tid = threadIdx.x, lane = tid & 63, w = tid >> 6;
    const int half = w >> 2;                 // 0 = H group, 1 = G group
    const int wr = (w >> 1) & 1, wc = w & 1; // 2x2 within group
    const int l15 = lane & 15, lhi = lane >> 4, lk = lane & 7;

    // XCD-bijective swizzle: nwg = 1536, 1536 % 8 == 0
    const int nwg = gridDim.x;
    const int cpx = nwg >> 3;
    const int swz = ((int)blockIdx.x & 7) * cpx + ((int)blockIdx.x >> 3);
    const int mt = swz & 15, nt = swz >> 4;  // mt fast: neighbors share B panels
    const int m0 = mt * 256, c0 = nt * 128;

    f32x4 acc[8][4];
#pragma unroll
    for (int i = 0; i < 8; ++i)
#pragma unroll
        for (int j = 0; j < 4; ++j) acc[i][j] = (f32x4){0.f, 0.f, 0.f, 0.f};

    const bf16_t* gA = xq + (size_t)m0 * DIN;
    const bf16_t* gH = wq + (size_t)c0 * DIN;
    const bf16_t* gG = wq + (size_t)(c0 + HALF) * DIN;

    // ---- prologue: stage tile 0 into buf0 (order A0, BH, BG, A1) ----
    STAGE_UNIT(gA, smem);
    STAGE_UNIT(gH, smem + 32768);
    STAGE_UNIT(gG, smem + 49152);
    STAGE_UNIT(gA + (size_t)128 * DIN, smem + 16384);
    WAITV(2);                 // A0, BH, BG landed (A1 still in flight)
    BAR();

    int cur = 0;
    for (int t = 0; t < NT; ++t) {
        // prefetch column (last iter re-stages tile NT-1 into dead buffer: keeps
        // per-wave vmcnt counts uniform; drained before smem reuse below)
        const int kc = (t + 1 < NT) ? (t + 1) * BK : t * BK;
        char* sw = smem + (cur ^ 1) * 65536;
        const char* sAc = smem + cur * 65536;
        const char* sBc = sAc + 32768 + half * 16384;

        bf16x8 a[4][2], b[4][2];

        // ---- P0: Mf0-3 x Nf0-1 ----
        LOAD_A(0); LOAD_B(0);
        STAGE_UNIT(gA + kc, sw);
        BAR(); LGKM0(); PRIO1(); MFMA_Q(0, 0); PRIO0(); BAR();
        // ---- P1: Mf0-3 x Nf2-3 ----
        LOAD_B(1);
        STAGE_UNIT(gH + kc, sw + 32768);
        BAR(); LGKM0(); PRIO1(); MFMA_Q(0, 1); PRIO0(); WAITV(4); BAR();
        // ---- P2: Mf4-7 x Nf0-1 ----
        LOAD_A(1);
        STAGE_UNIT(gG + kc, sw + 49152);
        BAR(); LGKM0(); PRIO1(); MFMA_Q(1, 0); PRIO0(); BAR();
        // ---- P3: Mf4-7 x Nf2-3 ----
        STAGE_UNIT(gA + (size_t)128 * DIN + kc, sw + 16384);
        BAR(); LGKM0(); PRIO1(); MFMA_Q(1, 1); PRIO0(); WAITV(2); BAR();

        cur ^= 1;
    }

    // ---- LoRA correction: one K=32 MFMA per fragment (RANK == 32) ----
    {
        bf16x8 tf[8];
#pragma unroll
        for (int m = 0; m < 8; ++m) {
            int row = m0 + (m >> 2) * 128 + wr * 64 + (m & 3) * 16 + l15;
            tf[m] = *reinterpret_cast<const bf16x8*>(T + (size_t)row * 32 + lhi * 8);
        }
#pragma unroll
        for (int n = 0; n < 4; ++n) {
            int ocol = c0 + half * HALF + wc * 64 + n * 16 + l15;
            bf16x8 lu = *reinterpret_cast<const bf16x8*>(lub + (size_t)ocol * 32 + lhi * 8);
#pragma unroll
            for (int m = 0; m < 8; ++m)
                acc[m][n] = __builtin_amdgcn_mfma_f32_16x16x32_bf16(tf[m], lu, acc[m][n], 0, 0, 0);
        }
    }

    // ---- GEGLU epilogue via LDS exchange (reuse all 128 KB as [256][128] f32) ----
    WAITV(0);                 // drain redundant last-tile staging before overwrite
    __syncthreads();
    float* exch = (float*)smem;
    if (half) {
#pragma unroll
        for (int m = 0; m < 8; ++m)
#pragma unroll
            for (int n = 0; n < 4; ++n) {
                int col = wc * 64 + n * 16 + l15;
#pragma unroll
                for (int r = 0; r < 4; ++r) {
                    int row = (m >> 2) * 128 + wr * 64 + (m & 3) * 16 + lhi * 4 + r;
                    float g = acc[m][n][r];
                    float gl = 0.5f * g * (1.0f + erff(g * 0.70710678118654752f));
                    exch[row * 128 + (col ^ (((row >> 2) & 3) << 4))] = gl;
                }
            }
    }
    __syncthreads();
    if (!half) {
#pragma unroll
        for (int m = 0; m < 8; ++m)
#pragma unroll
            for (int n = 0; n < 4; ++n) {
                int col = wc * 64 + n * 16 + l15;
#pragma unroll
                for (int r = 0; r < 4; ++r) {
                    int row = (m >> 2) * 128 + wr * 64 + (m & 3) * 16 + lhi * 4 + r;
                    float gl = exch[row * 128 + (col ^ (((row >> 2) & 3) << 4))];
                    out[(size_t)(m0 + row) * HALF + c0 + col] = acc[m][n][r] * gl;
                }
            }
    }
}

extern "C" void kernel_launch(void* const* d_in, const int* in_sizes, int n_in,
                              void* d_out, int out_size, void* d_ws, size_t ws_size,
                              hipStream_t stream) {
    const float* x  = (const float*)d_in[0];   // [1,4096,3072]
    const float* wr = (const float*)d_in[1];   // [24576,3072]
    const float* ld = (const float*)d_in[2];   // [32,3072]
    const float* lu = (const float*)d_in[3];   // [24576,32]
    float* out = (float*)d_out;                // [4096,12288] f32

    bf16_t* xq  = (bf16_t*)d_ws;
    bf16_t* wq  = xq + (size_t)MTOK * DIN;
    bf16_t* T   = wq + (size_t)NOUT * DIN;
    bf16_t* lub = T  + (size_t)MTOK * 32;

    k_quant_x<<<MTOK, 256, 0, stream>>>(x, xq);
    k_quant_w<<<(NOUT * (DIN / 4)) / 256, 256, 0, stream>>>(wr, wq);
    k_lora_t<<<MTOK / 8, 256, 0, stream>>>(x, ld, T);
    k_cvt_lu<<<(NOUT * 32 / 4) / 256, 256, 0, stream>>>(lu, lub);
    k_gemm<<<(MTOK / 256) * (HALF / 128), 512, 0, stream>>>(xq, wq, T, lub, out);
}

// Round 6
// 882.479 us; speedup vs baseline: 2.1080x; 1.0097x over previous
//
#include <hip/hip_runtime.h>
#include <hip/hip_bf16.h>
#include <math.h>

typedef __bf16 bf16_t;
typedef __bf16 bf16x4 __attribute__((ext_vector_type(4)));
typedef __bf16 bf16x8 __attribute__((ext_vector_type(8)));
typedef float  f32x4  __attribute__((ext_vector_type(4)));

#define DIN   3072
#define NOUT  24576
#define HALF  12288
#define MTOK  4096
#define BK    64
#define NT    48          // DIN / BK

#define GLD16(gp, lp) \
    __builtin_amdgcn_global_load_lds((const __attribute__((address_space(1))) void*)(gp), \
                                     (__attribute__((address_space(3))) void*)(lp), 16, 0, 0)

#define BAR()    __builtin_amdgcn_s_barrier()
#define LGKM0()  asm volatile("s_waitcnt lgkmcnt(0)" ::: "memory")
#define WAITV(N) asm volatile("s_waitcnt vmcnt(" #N ")" ::: "memory")
#define PRIO1()  __builtin_amdgcn_s_setprio(1)
#define PRIO0()  __builtin_amdgcn_s_setprio(0)

// ---------------- K1: per-token activation int4 fake-quant -> bf16 ----------------
__global__ __launch_bounds__(256) void k_quant_x(const float* __restrict__ x,
                                                 bf16_t* __restrict__ xq) {
    int m = blockIdx.x;
    int t = threadIdx.x;
    const float4* row = reinterpret_cast<const float4*>(x + (size_t)m * DIN);
    float4 v[3];
    float vm = 0.f;
#pragma unroll
    for (int i = 0; i < 3; ++i) {
        v[i] = row[t + i * 256];
        vm = fmaxf(vm, fmaxf(fmaxf(fabsf(v[i].x), fabsf(v[i].y)),
                             fmaxf(fabsf(v[i].z), fabsf(v[i].w))));
    }
#pragma unroll
    for (int d = 1; d < 64; d <<= 1) vm = fmaxf(vm, __shfl_xor(vm, d));
    __shared__ float sm[4];
    if ((t & 63) == 0) sm[t >> 6] = vm;
    __syncthreads();
    vm = fmaxf(fmaxf(sm[0], sm[1]), fmaxf(sm[2], sm[3]));
    float s = fmaxf(vm * (1.f / 7.f), 1e-8f);
    float inv = 1.f / s;
    bf16x4* orow = reinterpret_cast<bf16x4*>(xq + (size_t)m * DIN);
#pragma unroll
    for (int i = 0; i < 3; ++i) {
        bf16x4 o;
        o[0] = (bf16_t)(fminf(fmaxf(rintf(v[i].x * inv), -8.f), 7.f) * s);
        o[1] = (bf16_t)(fminf(fmaxf(rintf(v[i].y * inv), -8.f), 7.f) * s);
        o[2] = (bf16_t)(fminf(fmaxf(rintf(v[i].z * inv), -8.f), 7.f) * s);
        o[3] = (bf16_t)(fminf(fmaxf(rintf(v[i].w * inv), -8.f), 7.f) * s);
        orow[t + i * 256] = o;
    }
}

// ---------------- K2: per-(row, group-of-64) weight int4 fake-quant -> bf16 -------
__global__ __launch_bounds__(256) void k_quant_w(const float* __restrict__ w,
                                                 bf16_t* __restrict__ wq) {
    size_t idx = (size_t)blockIdx.x * 256 + threadIdx.x;  // float4 index
    float4 v = reinterpret_cast<const float4*>(w)[idx];
    float vm = fmaxf(fmaxf(fabsf(v.x), fabsf(v.y)), fmaxf(fabsf(v.z), fabsf(v.w)));
    vm = fmaxf(vm, __shfl_xor(vm, 1));
    vm = fmaxf(vm, __shfl_xor(vm, 2));
    vm = fmaxf(vm, __shfl_xor(vm, 4));
    vm = fmaxf(vm, __shfl_xor(vm, 8));
    float s = fmaxf(vm * (1.f / 7.f), 1e-8f);
    float inv = 1.f / s;
    bf16x4 o;
    o[0] = (bf16_t)(fminf(fmaxf(rintf(v.x * inv), -8.f), 7.f) * s);
    o[1] = (bf16_t)(fminf(fmaxf(rintf(v.y * inv), -8.f), 7.f) * s);
    o[2] = (bf16_t)(fminf(fmaxf(rintf(v.z * inv), -8.f), 7.f) * s);
    o[3] = (bf16_t)(fminf(fmaxf(rintf(v.w * inv), -8.f), 7.f) * s);
    reinterpret_cast<bf16x4*>(wq)[idx] = o;
}

// ---------------- K3: T = x @ lora_down^T  (full-precision x), bf16 out -----------
__global__ __launch_bounds__(256) void k_lora_t(const float* __restrict__ x,
                                                const float* __restrict__ ld,
                                                bf16_t* __restrict__ T) {
    int r = threadIdx.x & 31;
    int m = blockIdx.x * 8 + (threadIdx.x >> 5);
    const float4* xr = reinterpret_cast<const float4*>(x + (size_t)m * DIN);
    const float4* lr = reinterpret_cast<const float4*>(ld + (size_t)r * DIN);
    float acc = 0.f;
#pragma unroll 4
    for (int i = 0; i < DIN / 4; ++i) {
        float4 a = xr[i], b = lr[i];
        acc += a.x * b.x + a.y * b.y + a.z * b.z + a.w * b.w;
    }
    T[(size_t)m * 32 + r] = (bf16_t)acc;
}

// ---------------- K3b: cast lora_up f32 -> bf16 -----------------------------------
__global__ __launch_bounds__(256) void k_cvt_lu(const float* __restrict__ lu,
                                                bf16_t* __restrict__ lub) {
    size_t idx = (size_t)blockIdx.x * 256 + threadIdx.x;  // float4 index
    float4 v = reinterpret_cast<const float4*>(lu)[idx];
    bf16x4 o;
    o[0] = (bf16_t)v.x; o[1] = (bf16_t)v.y; o[2] = (bf16_t)v.z; o[3] = (bf16_t)v.w;
    reinterpret_cast<bf16x4*>(lub)[idx] = o;
}

// ---------------- K4: balanced 4-phase fused GEMM (T2+T3+T4+T5) -------------------
// Tile 256 rows x (128 H + 128 G cols). 8 waves: 0-3 H, 4-7 G, 2x2 each.
// LDS dbuf 2 x {A0 16K | A1 16K | BH 16K | BG 16K} = 128 KB.
// Stage issue per K-tile: P0->A0', P1->BH', P2->BG', P3->A1'.
// Wait schedule (FIFO-verified, 2 loads/unit):
//   prologue WAITV(2): A0,BH,BG landed, A1 in flight.
//   end-P1 WAITV(4): A1(t) landed  (consumed P2's LOADA a2)
//   end-P2 WAITV(4): A0(t+1) landed (consumed P3's cross-tile LOADA aP)
//   end-P3 WAITV(2): BH',BG' landed (consumed next P0/P1 LOADB)  <- r5 bug was (4)
// Global src pointers hoisted once, advanced +BK/tile.

#define LOADA(dst, mh, base)                                                  \
    _Pragma("unroll")                                                         \
    for (int _i = 0; _i < 4; ++_i) {                                          \
        _Pragma("unroll")                                                     \
        for (int _ks = 0; _ks < 2; ++_ks) {                                   \
            int _ra = (mh) * 128 + wr * 64 + _i * 16 + l15;                   \
            dst[_i][_ks] = *(const bf16x8*)((base) + _ra * 128 +              \
                                            (((_ks * 4 + lhi) ^ lk) << 4));   \
        }                                                                     \
    }

#define LOADB(dst, nh, base)                                                  \
    _Pragma("unroll")                                                         \
    for (int _j = 0; _j < 2; ++_j) {                                          \
        _Pragma("unroll")                                                     \
        for (int _ks = 0; _ks < 2; ++_ks) {                                   \
            int _rb = wc * 64 + ((nh) * 2 + _j) * 16 + l15;                   \
            dst[_j][_ks] = *(const bf16x8*)((base) + _rb * 128 +              \
                                            (((_ks * 4 + lhi) ^ lk) << 4));   \
        }                                                                     \
    }

#define MFMAQ(mh, nh, A, B)                                                   \
    _Pragma("unroll")                                                         \
    for (int _i = 0; _i < 4; ++_i) {                                          \
        _Pragma("unroll")                                                     \
        for (int _j = 0; _j < 2; ++_j) {                                      \
            _Pragma("unroll")                                                 \
            for (int _ks = 0; _ks < 2; ++_ks) {                               \
                acc[(mh) * 4 + _i][(nh) * 2 + _j] =                           \
                    __builtin_amdgcn_mfma_f32_16x16x32_bf16(                  \
                        A[_i][_ks], B[_j][_ks],                               \
                        acc[(mh) * 4 + _i][(nh) * 2 + _j], 0, 0, 0);          \
            }                                                                 \
        }                                                                     \
    }

#define STG(pl, ph, off)                                                      \
    do {                                                                      \
        GLD16((pl), swc + (off) + wq4);                                       \
        GLD16((ph), swc + (off) + wq4 + 8192);                                \
    } while (0)

__global__ __launch_bounds__(512, 2) void k_gemm(const bf16_t* __restrict__ xq,
                                                 const bf16_t* __restrict__ wq,
                                                 const bf16_t* __restrict__ T,
                                                 const bf16_t* __restrict__ lub,
                                                 float* __restrict__ out) {
    __shared__ __align__(16) char smem[131072];

    const int tid = threadIdx.x, lane = tid & 63, w = tid >> 6;
    const int half = w >> 2;                 // 0 = H group, 1 = G group
    const int wr = (w >> 1) & 1, wc = w & 1; // 2x2 within group
    const int l15 = lane & 15, lhi = lane >> 4, lk = lane & 7;
    const int wq4 = w * 1024;                // wave-uniform LDS sub-base

    // XCD-bijective swizzle: nwg = 1536, 1536 % 8 == 0
    const int nwg = gridDim.x;
    const int cpx = nwg >> 3;
    const int swz = ((int)blockIdx.x & 7) * cpx + ((int)blockIdx.x >> 3);
    const int mt = swz & 15, nt = swz >> 4;  // mt fast: neighbors share B panels
    const int m0 = mt * 256, c0 = nt * 128;

    f32x4 acc[8][4];
#pragma unroll
    for (int i = 0; i < 8; ++i)
#pragma unroll
        for (int j = 0; j < 4; ++j) acc[i][j] = (f32x4){0.f, 0.f, 0.f, 0.f};

    // hoisted per-thread global source pointers (both-sides swizzle folded in;
    // row+64k == row mod 8 -> same XOR column for lo/hi chunk)
    const int srow = tid >> 3;
    const int sgc = ((tid & 7) ^ (srow & 7)) * 8;
    const bf16_t* pA0l = xq + (size_t)(m0 + srow) * DIN + sgc;
    const bf16_t* pA0h = pA0l + (size_t)64 * DIN;
    const bf16_t* pA1l = pA0l + (size_t)128 * DIN;
    const bf16_t* pA1h = pA0l + (size_t)192 * DIN;
    const bf16_t* pHl  = wq + (size_t)(c0 + srow) * DIN + sgc;
    const bf16_t* pHh  = pHl + (size_t)64 * DIN;
    const bf16_t* pGl  = pHl + (size_t)HALF * DIN;
    const bf16_t* pGh  = pGl + (size_t)64 * DIN;

    bf16x8 aP[4][2], a2[4][2], b0[2][2], b1[2][2];

    // ---- prologue: stage tile 0 into buf0 (A0, BH, BG, A1), preload aP ----
    {
        char* swc = (char*)smem;             // buf0
        STG(pA0l, pA0h, 0);
        STG(pHl, pHh, 32768);
        STG(pGl, pGh, 49152);
        STG(pA1l, pA1h, 16384);
    }
    pA0l += BK; pA0h += BK; pA1l += BK; pA1h += BK;
    pHl += BK; pHh += BK; pGl += BK; pGh += BK;
    WAITV(2);                 // A0, BH, BG landed (A1 still in flight)
    BAR();
    LOADA(aP, 0, (const char*)smem);

    int cur = 0;
    for (int t = 0; t < NT; ++t) {
        const char* sAc = (const char*)smem + (cur << 16);
        const char* sBc = sAc + 32768 + (half << 14);
        char* swc = (char*)smem + ((cur ^ 1) << 16);

        // ---- P0: MFMA quadrant (0,0) ----
        LOADB(b0, 0, sBc);
        STG(pA0l, pA0h, 0);
        BAR(); LGKM0(); PRIO1(); MFMAQ(0, 0, aP, b0); PRIO0(); WAITV(4); BAR();
        // ---- P1: (0,1) ----
        LOADB(b1, 1, sBc);
        STG(pHl, pHh, 32768);
        BAR(); LGKM0(); PRIO1(); MFMAQ(0, 1, aP, b1); PRIO0(); WAITV(4); BAR();
        // ---- P2: (1,0) ----
        LOADA(a2, 1, sAc);
        STG(pGl, pGh, 49152);
        BAR(); LGKM0(); PRIO1(); MFMAQ(1, 0, a2, b0); PRIO0(); WAITV(4); BAR();
        // ---- P3: (1,1) + cross-tile aP prefetch from just-staged buffer ----
        STG(pA1l, pA1h, 16384);
        BAR(); LGKM0(); PRIO1(); MFMAQ(1, 1, a2, b1); PRIO0();
        LOADA(aP, 0, (const char*)swc);      // next-tile A0 (landed per end-P2 wait)
        WAITV(2); BAR();                     // BH', BG' landed for next P0/P1

        const int adv = (t + 2 < NT) ? BK : 0;   // clamp: last iter re-stages NT-1
        pA0l += adv; pA0h += adv; pA1l += adv; pA1h += adv;
        pHl += adv; pHh += adv; pGl += adv; pGh += adv;
        cur ^= 1;
    }

    // ---- LoRA correction: one K=32 MFMA per fragment (RANK == 32) ----
    {
        bf16x8 tf[8];
#pragma unroll
        for (int m = 0; m < 8; ++m) {
            int row = m0 + (m >> 2) * 128 + wr * 64 + (m & 3) * 16 + l15;
            tf[m] = *reinterpret_cast<const bf16x8*>(T + (size_t)row * 32 + lhi * 8);
        }
#pragma unroll
        for (int n = 0; n < 4; ++n) {
            int ocol = c0 + half * HALF + wc * 64 + n * 16 + l15;
            bf16x8 lu = *reinterpret_cast<const bf16x8*>(lub + (size_t)ocol * 32 + lhi * 8);
#pragma unroll
            for (int m = 0; m < 8; ++m)
                acc[m][n] = __builtin_amdgcn_mfma_f32_16x16x32_bf16(tf[m], lu, acc[m][n], 0, 0, 0);
        }
    }

    // ---- GEGLU epilogue via LDS exchange (reuse all 128 KB as [256][128] f32) ----
    WAITV(0);                 // drain redundant last-tile staging before overwrite
    __syncthreads();
    float* exch = (float*)smem;
    if (half) {
#pragma unroll
        for (int m = 0; m < 8; ++m)
#pragma unroll
            for (int n = 0; n < 4; ++n) {
                int col = wc * 64 + n * 16 + l15;
#pragma unroll
                for (int r = 0; r < 4; ++r) {
                    int row = (m >> 2) * 128 + wr * 64 + (m & 3) * 16 + lhi * 4 + r;
                    float g = acc[m][n][r];
                    float gl = 0.5f * g * (1.0f + erff(g * 0.70710678118654752f));
                    exch[row * 128 + (col ^ (((row >> 2) & 3) << 4))] = gl;
                }
            }
    }
    __syncthreads();
    if (!half) {
#pragma unroll
        for (int m = 0; m < 8; ++m)
#pragma unroll
            for (int n = 0; n < 4; ++n) {
                int col = wc * 64 + n * 16 + l15;
#pragma unroll
                for (int r = 0; r < 4; ++r) {
                    int row = (m >> 2) * 128 + wr * 64 + (m & 3) * 16 + lhi * 4 + r;
                    float gl = exch[row * 128 + (col ^ (((row >> 2) & 3) << 4))];
                    out[(size_t)(m0 + row) * HALF + c0 + col] = acc[m][n][r] * gl;
                }
            }
    }
}

extern "C" void kernel_launch(void* const* d_in, const int* in_sizes, int n_in,
                              void* d_out, int out_size, void* d_ws, size_t ws_size,
                              hipStream_t stream) {
    const float* x  = (const float*)d_in[0];   // [1,4096,3072]
    const float* wr = (const float*)d_in[1];   // [24576,3072]
    const float* ld = (const float*)d_in[2];   // [32,3072]
    const float* lu = (const float*)d_in[3];   // [24576,32]
    float* out = (float*)d_out;                // [4096,12288] f32

    bf16_t* xq  = (bf16_t*)d_ws;
    bf16_t* wq  = xq + (size_t)MTOK * DIN;
    bf16_t* T   = wq + (size_t)NOUT * DIN;
    bf16_t* lub = T  + (size_t)MTOK * 32;

    k_quant_x<<<MTOK, 256, 0, stream>>>(x, xq);
    k_quant_w<<<(NOUT * (DIN / 4)) / 256, 256, 0, stream>>>(wr, wq);
    k_lora_t<<<MTOK / 8, 256, 0, stream>>>(x, ld, T);
    k_cvt_lu<<<(NOUT * 32 / 4) / 256, 256, 0, stream>>>(lu, lub);
    k_gemm<<<(MTOK / 256) * (HALF / 128), 512, 0, stream>>>(xq, wq, T, lub, out);
}